// Round 1
// baseline (56.717 us; speedup 1.0000x reference)
//
#include <hip/hip_runtime.h>
#include <stdint.h>

typedef __attribute__((ext_vector_type(8))) short     bf16x8;
typedef __attribute__((ext_vector_type(4))) float     f32x4;
typedef __attribute__((ext_vector_type(4))) float     float4v;
typedef __attribute__((ext_vector_type(2))) unsigned  uint2v;
typedef __attribute__((ext_vector_type(4))) unsigned  uint4v;

#define DEVINL static __device__ __forceinline__

#define B_  2
#define H_  8
#define S_  2048
#define D_  64
#define NKT (S_ / 64)

DEVINL unsigned short f2bf(float f) {
  union { float f; unsigned u; } v; v.f = f;
  unsigned r = v.u + 0x7FFFu + ((v.u >> 16) & 1u);   // RNE
  return (unsigned short)(r >> 16);
}

DEVINL void gload_lds16(const void* g, void* l) {
  __builtin_amdgcn_global_load_lds(
      (const __attribute__((address_space(1))) void*)g,
      (__attribute__((address_space(3))) void*)l, 16, 0, 0);
}

// ---------------- prep: K fp32->bf16 (same layout), V fp32->bf16 transposed [b][d][s] ----------------
__global__ __launch_bounds__(256) void prep_kernel(
    const float* __restrict__ K, const float* __restrict__ V,
    unsigned short* __restrict__ Kb, unsigned short* __restrict__ Vt) {
  const int t = threadIdx.x;
  if (blockIdx.x < 128) {
    // K convert: 2*2048*64 = 262144 elems, 2048 per block, 8 per thread
    const int base = blockIdx.x * 2048 + t * 8;
    const float4v a = *(const float4v*)(K + base);
    const float4v b = *(const float4v*)(K + base + 4);
    uint4v o;
    o.x = (unsigned)f2bf(a.x) | ((unsigned)f2bf(a.y) << 16);
    o.y = (unsigned)f2bf(a.z) | ((unsigned)f2bf(a.w) << 16);
    o.z = (unsigned)f2bf(b.x) | ((unsigned)f2bf(b.y) << 16);
    o.w = (unsigned)f2bf(b.z) | ((unsigned)f2bf(b.w) << 16);
    *(uint4v*)(Kb + base) = o;
  } else {
    __shared__ float Vf[64][65];                 // +1 pad: conflict-free transpose
    const int vb   = blockIdx.x - 128;           // 0..63
    const int b    = vb >> 5;
    const int sblk = vb & 31;
    const int r = t >> 2, c = t & 3;
    const float* src = V + ((size_t)(b * S_ + sblk * 64 + r)) * 64 + c * 16;
#pragma unroll
    for (int j = 0; j < 4; ++j) {
      float4v x = *(const float4v*)(src + 4 * j);
      Vf[r][c * 16 + 4 * j + 0] = x.x;
      Vf[r][c * 16 + 4 * j + 1] = x.y;
      Vf[r][c * 16 + 4 * j + 2] = x.z;
      Vf[r][c * 16 + 4 * j + 3] = x.w;
    }
    __syncthreads();
    unsigned short o[16];
#pragma unroll
    for (int j = 0; j < 16; ++j) o[j] = f2bf(Vf[c * 16 + j][r]);   // Vt row d=r, keys c*16+j
    unsigned short* dst = Vt + ((size_t)(b * 64 + r)) * S_ + sblk * 64 + c * 16;
    uint4v w0, w1;
    w0.x = (unsigned)o[0]  | ((unsigned)o[1]  << 16);
    w0.y = (unsigned)o[2]  | ((unsigned)o[3]  << 16);
    w0.z = (unsigned)o[4]  | ((unsigned)o[5]  << 16);
    w0.w = (unsigned)o[6]  | ((unsigned)o[7]  << 16);
    w1.x = (unsigned)o[8]  | ((unsigned)o[9]  << 16);
    w1.y = (unsigned)o[10] | ((unsigned)o[11] << 16);
    w1.z = (unsigned)o[12] | ((unsigned)o[13] << 16);
    w1.w = (unsigned)o[14] | ((unsigned)o[15] << 16);
    *(uint4v*)(dst)     = w0;
    *(uint4v*)(dst + 8) = w1;
  }
}

// ---------------- main attention kernel ----------------
__global__ __launch_bounds__(256, 2) void attn_kernel(
    const float* __restrict__ Q, const unsigned short* __restrict__ Kb,
    const unsigned short* __restrict__ Vt, float* __restrict__ O) {
  __shared__ __align__(16) unsigned short Klds[2][4096];   // [key][d] bf16, XOR-swizzled 16B slots
  __shared__ __align__(16) unsigned short Vlds[2][4096];   // [d][key] bf16, XOR-swizzled
  __shared__ __align__(16) unsigned short Plds[4][16 * 72]; // per-wave P, stride 72 (bank-floor)

  const int bid = blockIdx.x;
  const int b  = bid >> 8;
  const int h  = (bid >> 5) & 7;
  const int qt = bid & 31;

  const int tid  = threadIdx.x;
  const int lane = tid & 63;
  const int wave = tid >> 6;
  const int g    = lane >> 4;    // k-chunk group (0..3)
  const int ql   = lane & 15;    // row/col within 16

  const unsigned short* Kbase = Kb + (size_t)b * (S_ * 64);
  const unsigned short* Vbase = Vt + (size_t)b * (64 * S_);

  // ---- Q fragments (scaled by 1/sqrt(D) * log2(e)), held in registers ----
  const float qscale = 0.125f * 1.4426950408889634f;
  const float* qrow = Q + ((size_t)((b * H_ + h) * S_) + (size_t)(qt * 64 + wave * 16 + ql)) * 64;
  bf16x8 qfrag[2];
#pragma unroll
  for (int s = 0; s < 2; ++s) {
    const float* p = qrow + s * 32 + g * 8;
    float4v x0 = *(const float4v*)(p);
    float4v x1 = *(const float4v*)(p + 4);
    bf16x8 f;
    f[0] = (short)f2bf(x0.x * qscale); f[1] = (short)f2bf(x0.y * qscale);
    f[2] = (short)f2bf(x0.z * qscale); f[3] = (short)f2bf(x0.w * qscale);
    f[4] = (short)f2bf(x1.x * qscale); f[5] = (short)f2bf(x1.y * qscale);
    f[6] = (short)f2bf(x1.z * qscale); f[7] = (short)f2bf(x1.w * qscale);
    qfrag[s] = f;
  }

  // staging constants: lane covers 16B slot (lane&7) of row (lane>>3) within a 8-row segment.
  // LDS dest is linear (base + lane*16); the XOR swizzle is applied to the GLOBAL source (rule #21).
  const int srow  = lane >> 3;                 // 0..7
  const int sperm = (lane & 7) ^ srow;         // source 16B-chunk permutation

  f32x4 acc[4];
#pragma unroll
  for (int nt = 0; nt < 4; ++nt) acc[nt] = (f32x4){0.f, 0.f, 0.f, 0.f};
  float mrun = -__builtin_inff();
  float lrun = 0.f;

  // prologue: stage tile 0 into buf 0
#pragma unroll
  for (int i = 0; i < 2; ++i) {
    const int seg = wave * 2 + i;              // 0..7 (8 rows each)
    gload_lds16(Kbase + (size_t)(seg * 8 + srow) * 64 + sperm * 8,
                &Klds[0][seg * 512 + lane * 8]);
    gload_lds16(Vbase + (size_t)(seg * 8 + srow) * S_ + sperm * 8,
                &Vlds[0][seg * 512 + lane * 8]);
  }

  int buf = 0;
  for (int kt = 0; kt < NKT; ++kt) {
    __syncthreads();   // drains vmcnt -> buf staged; all waves done reading buf^1

    if (kt + 1 < NKT) {
#pragma unroll
      for (int i = 0; i < 2; ++i) {
        const int seg = wave * 2 + i;
        gload_lds16(Kbase + (size_t)(kt + 1) * 4096 + (size_t)(seg * 8 + srow) * 64 + sperm * 8,
                    &Klds[buf ^ 1][seg * 512 + lane * 8]);
        gload_lds16(Vbase + (size_t)(seg * 8 + srow) * S_ + (size_t)(kt + 1) * 64 + sperm * 8,
                    &Vlds[buf ^ 1][seg * 512 + lane * 8]);
      }
    }

    // ---- QK^T (swapped): sc[mt] = scores^T tile, keys mt*16+4g+r, q=ql ----
    f32x4 sc[4];
#pragma unroll
    for (int mt = 0; mt < 4; ++mt) sc[mt] = (f32x4){0.f, 0.f, 0.f, 0.f};
#pragma unroll
    for (int s = 0; s < 2; ++s) {
#pragma unroll
      for (int mt = 0; mt < 4; ++mt) {
        const int key  = mt * 16 + ql;
        const int slot = (g + 4 * s) ^ (key & 7);
        const bf16x8 a = *(const bf16x8*)&Klds[buf][key * 64 + slot * 8];
        sc[mt] = __builtin_amdgcn_mfma_f32_16x16x32_bf16(a, qfrag[s], sc[mt], 0, 0, 0);
      }
    }

    // ---- online softmax (base 2) ----
    float mx = sc[0][0];
#pragma unroll
    for (int mt = 0; mt < 4; ++mt)
#pragma unroll
      for (int r = 0; r < 4; ++r) mx = fmaxf(mx, sc[mt][r]);
    mx = fmaxf(mx, __shfl_xor(mx, 16));
    mx = fmaxf(mx, __shfl_xor(mx, 32));
    const float mnew = fmaxf(mrun, mx);
    const float fac  = __builtin_amdgcn_exp2f(mrun - mnew);

    float psum = 0.f;
#pragma unroll
    for (int mt = 0; mt < 4; ++mt) {
      const float p0 = __builtin_amdgcn_exp2f(sc[mt][0] - mnew);
      const float p1 = __builtin_amdgcn_exp2f(sc[mt][1] - mnew);
      const float p2 = __builtin_amdgcn_exp2f(sc[mt][2] - mnew);
      const float p3 = __builtin_amdgcn_exp2f(sc[mt][3] - mnew);
      psum += (p0 + p1) + (p2 + p3);
      uint2v w;
      w.x = (unsigned)f2bf(p0) | ((unsigned)f2bf(p1) << 16);
      w.y = (unsigned)f2bf(p2) | ((unsigned)f2bf(p3) << 16);
      *(uint2v*)&Plds[wave][ql * 72 + mt * 16 + g * 4] = w;   // P[q=ql][key=mt*16+4g+r]
    }
    psum += __shfl_xor(psum, 16);
    psum += __shfl_xor(psum, 32);
    lrun = lrun * fac + psum;
    mrun = mnew;

    // rescale accumulators: acc rows are q=4g+r; factors live on lanes ql==q
    float facr[4];
#pragma unroll
    for (int r = 0; r < 4; ++r) facr[r] = __shfl(fac, g * 4 + r);
#pragma unroll
    for (int nt = 0; nt < 4; ++nt)
#pragma unroll
      for (int r = 0; r < 4; ++r) acc[nt][r] *= facr[r];

    // ---- PV: acc[nt] += P(16q x 32key) * V(32key x 16d) ----
#pragma unroll
    for (int s = 0; s < 2; ++s) {
      const bf16x8 pa = *(const bf16x8*)&Plds[wave][ql * 72 + s * 32 + g * 8];
#pragma unroll
      for (int nt = 0; nt < 4; ++nt) {
        const int d    = nt * 16 + ql;
        const int slot = (g + 4 * s) ^ (d & 7);
        const bf16x8 bv = *(const bf16x8*)&Vlds[buf][d * 64 + slot * 8];
        acc[nt] = __builtin_amdgcn_mfma_f32_16x16x32_bf16(pa, bv, acc[nt], 0, 0, 0);
      }
    }

    buf ^= 1;
  }

  // ---- epilogue: divide by l, write out ----
  float inv[4];
#pragma unroll
  for (int r = 0; r < 4; ++r) inv[r] = 1.f / __shfl(lrun, g * 4 + r);
  float* obase = O + ((size_t)((b * H_ + h) * S_) + (size_t)(qt * 64 + wave * 16)) * 64;
#pragma unroll
  for (int nt = 0; nt < 4; ++nt)
#pragma unroll
    for (int r = 0; r < 4; ++r)
      obase[(size_t)(4 * g + r) * 64 + nt * 16 + ql] = acc[nt][r] * inv[r];
}

extern "C" void kernel_launch(void* const* d_in, const int* in_sizes, int n_in,
                              void* d_out, int out_size, void* d_ws, size_t ws_size,
                              hipStream_t stream) {
  const float* Q = (const float*)d_in[0];
  const float* K = (const float*)d_in[1];
  const float* V = (const float*)d_in[2];
  float* O = (float*)d_out;

  unsigned short* Kb = (unsigned short*)d_ws;                 // B*S*64 bf16 = 512 KiB
  unsigned short* Vt = Kb + (size_t)B_ * S_ * 64;             // B*64*S bf16 = 512 KiB

  prep_kernel<<<192, 256, 0, stream>>>(K, V, Kb, Vt);
  attn_kernel<<<B_ * H_ * (S_ / 64), 256, 0, stream>>>(Q, Kb, Vt, O);
}

// Round 3
// 46.500 us; speedup vs baseline: 1.2197x; 1.2197x over previous
//
#include <hip/hip_runtime.h>
#include <stdint.h>

typedef __attribute__((ext_vector_type(8))) short     bf16x8;
typedef __attribute__((ext_vector_type(4))) float     f32x4;
typedef __attribute__((ext_vector_type(4))) float     float4v;
typedef __attribute__((ext_vector_type(2))) unsigned  uint2v;
typedef __attribute__((ext_vector_type(4))) unsigned  uint4v;

#define DEVINL static __device__ __forceinline__

#define B_  2
#define H_  8
#define S_  2048
#define D_  64
#define KVB 128
#define NKT (S_ / KVB)

DEVINL unsigned short f2bf(float f) {
  union { float f; unsigned u; } v; v.f = f;
  unsigned r = v.u + 0x7FFFu + ((v.u >> 16) & 1u);   // RNE
  return (unsigned short)(r >> 16);
}

DEVINL void gload_lds16(const void* g, void* l) {
  __builtin_amdgcn_global_load_lds(
      (const __attribute__((address_space(1))) void*)g,
      (__attribute__((address_space(3))) void*)l, 16, 0, 0);
}

// ---------------- prep: K fp32->bf16 (same layout), V fp32->bf16 transposed [b][d][s] ----------------
__global__ __launch_bounds__(256) void prep_kernel(
    const float* __restrict__ K, const float* __restrict__ V,
    unsigned short* __restrict__ Kb, unsigned short* __restrict__ Vt) {
  const int t = threadIdx.x;
  if (blockIdx.x < 128) {
    const int base = blockIdx.x * 2048 + t * 8;
    const float4v a = *(const float4v*)(K + base);
    const float4v b = *(const float4v*)(K + base + 4);
    uint4v o;
    o.x = (unsigned)f2bf(a.x) | ((unsigned)f2bf(a.y) << 16);
    o.y = (unsigned)f2bf(a.z) | ((unsigned)f2bf(a.w) << 16);
    o.z = (unsigned)f2bf(b.x) | ((unsigned)f2bf(b.y) << 16);
    o.w = (unsigned)f2bf(b.z) | ((unsigned)f2bf(b.w) << 16);
    *(uint4v*)(Kb + base) = o;
  } else {
    __shared__ float Vf[64][65];
    const int vb   = blockIdx.x - 128;
    const int b    = vb >> 5;
    const int sblk = vb & 31;
    const int r = t >> 2, c = t & 3;
    const float* src = V + ((size_t)(b * S_ + sblk * 64 + r)) * 64 + c * 16;
#pragma unroll
    for (int j = 0; j < 4; ++j) {
      float4v x = *(const float4v*)(src + 4 * j);
      Vf[r][c * 16 + 4 * j + 0] = x.x;
      Vf[r][c * 16 + 4 * j + 1] = x.y;
      Vf[r][c * 16 + 4 * j + 2] = x.z;
      Vf[r][c * 16 + 4 * j + 3] = x.w;
    }
    __syncthreads();
    unsigned short o[16];
#pragma unroll
    for (int j = 0; j < 16; ++j) o[j] = f2bf(Vf[c * 16 + j][r]);
    unsigned short* dst = Vt + ((size_t)(b * 64 + r)) * S_ + sblk * 64 + c * 16;
    uint4v w0, w1;
    w0.x = (unsigned)o[0]  | ((unsigned)o[1]  << 16);
    w0.y = (unsigned)o[2]  | ((unsigned)o[3]  << 16);
    w0.z = (unsigned)o[4]  | ((unsigned)o[5]  << 16);
    w0.w = (unsigned)o[6]  | ((unsigned)o[7]  << 16);
    w1.x = (unsigned)o[8]  | ((unsigned)o[9]  << 16);
    w1.y = (unsigned)o[10] | ((unsigned)o[11] << 16);
    w1.z = (unsigned)o[12] | ((unsigned)o[13] << 16);
    w1.w = (unsigned)o[14] | ((unsigned)o[15] << 16);
    *(uint4v*)(dst)     = w0;
    *(uint4v*)(dst + 8) = w1;
  }
}

// ---------------- main attention kernel: KVB=128 per phase ----------------
__global__ __launch_bounds__(256, 2) void attn_kernel(
    const float* __restrict__ Q, const unsigned short* __restrict__ Kb,
    const unsigned short* __restrict__ Vt, float* __restrict__ O) {
  // K: [128 keys][64 d]  (128B rows, 8x16B slots, slot ^= key&7)
  // V: [64 d][128 keys]  (256B rows, 16x16B chunks, chunk ^= d&7 on low 3 bits)
  // P: per-wave [16 q][128 keys] (256B rows, chunk ^= q&7 on low 3 bits)
  __shared__ __align__(16) unsigned short Klds[2][8192];
  __shared__ __align__(16) unsigned short Vlds[2][8192];
  __shared__ __align__(16) unsigned short Plds[4][2048];

  const int bid = blockIdx.x;
  const int b  = bid >> 8;
  const int h  = (bid >> 5) & 7;
  const int qt = bid & 31;

  const int tid  = threadIdx.x;
  const int lane = tid & 63;
  const int wave = tid >> 6;
  const int g    = lane >> 4;       // 0..3
  const int ql   = lane & 15;       // 0..15
  const int qx   = ql & 7;
  const int gh   = g >> 1;          // 0..1
  const int glo  = g & 1;           // 0..1

  const unsigned short* Kbase = Kb + (size_t)b * (S_ * 64);
  const unsigned short* Vbase = Vt + (size_t)b * (64 * S_);

  // ---- Q fragments (scaled by 1/sqrt(D) * log2(e)) ----
  const float qscale = 0.125f * 1.4426950408889634f;
  const float* qrow = Q + ((size_t)((b * H_ + h) * S_) + (size_t)(qt * 64 + wave * 16 + ql)) * 64;
  bf16x8 qfrag[2];
#pragma unroll
  for (int s = 0; s < 2; ++s) {
    const float* p = qrow + s * 32 + g * 8;
    float4v x0 = *(const float4v*)(p);
    float4v x1 = *(const float4v*)(p + 4);
    bf16x8 f;
    f[0] = (short)f2bf(x0.x * qscale); f[1] = (short)f2bf(x0.y * qscale);
    f[2] = (short)f2bf(x0.z * qscale); f[3] = (short)f2bf(x0.w * qscale);
    f[4] = (short)f2bf(x1.x * qscale); f[5] = (short)f2bf(x1.y * qscale);
    f[6] = (short)f2bf(x1.z * qscale); f[7] = (short)f2bf(x1.w * qscale);
    qfrag[s] = f;
  }

  // ones fragment for the l-sum MFMA (B[k][col] = 1.0 everywhere)
  bf16x8 ones;
#pragma unroll
  for (int j = 0; j < 8; ++j) ones[j] = (short)0x3F80;

  // staging lane constants (rule #21: linear LDS dest, inverse-XOR global source)
  const int krow   = lane >> 3;                     // K: 8 rows per instr
  const int kchunk = (lane & 7) ^ krow;             // K source 16B-chunk
  const int vrow   = lane >> 4;                     // V: 4 rows per instr

  f32x4 acc[4];
#pragma unroll
  for (int nt = 0; nt < 4; ++nt) acc[nt] = (f32x4){0.f, 0.f, 0.f, 0.f};
  f32x4 acc5 = (f32x4){0.f, 0.f, 0.f, 0.f};         // row-sums (l) via MFMA
  float mrun = -__builtin_inff();

#define STAGE(BUF, KT)                                                                     \
  do {                                                                                     \
    _Pragma("unroll")                                                                      \
    for (int i = 0; i < 4; ++i) {                                                          \
      gload_lds16(Kbase + (size_t)((KT) * KVB + 32 * wave + 8 * i + krow) * 64 + kchunk * 8, \
                  &Klds[BUF][2048 * wave + 512 * i + lane * 8]);                           \
      const int vch = (lane & 15) ^ vrow ^ (4 * (i & 1));                                  \
      gload_lds16(Vbase + (size_t)(16 * wave + 4 * i + vrow) * S_ + (KT) * KVB + vch * 8,  \
                  &Vlds[BUF][2048 * wave + 512 * i + lane * 8]);                           \
    }                                                                                      \
  } while (0)

  STAGE(0, 0);

  int buf = 0;
  for (int kt = 0; kt < NKT; ++kt) {
    __syncthreads();   // tile kt staged & everyone done reading buf^1

    if (kt + 1 < NKT) STAGE(buf ^ 1, kt + 1);

    // ---- QK^T (swapped): sc[mt] rows = keys mt*16+4g+r, cols = q = ql ----
    f32x4 sc[8];
#pragma unroll
    for (int mt = 0; mt < 8; ++mt) sc[mt] = (f32x4){0.f, 0.f, 0.f, 0.f};
    __builtin_amdgcn_s_setprio(1);
#pragma unroll
    for (int s = 0; s < 2; ++s) {
#pragma unroll
      for (int mt = 0; mt < 8; ++mt) {
        const bf16x8 a = *(const bf16x8*)&Klds[buf][(mt * 16 + ql) * 64 + ((s * 4 + g) ^ qx) * 8];
        sc[mt] = __builtin_amdgcn_mfma_f32_16x16x32_bf16(a, qfrag[s], sc[mt], 0, 0, 0);
      }
    }
    __builtin_amdgcn_s_setprio(0);

    // ---- per-q row max over 32 local values, reduce across g groups ----
    float mx = fmaxf(fmaxf(sc[0][0], sc[0][1]), fmaxf(sc[0][2], sc[0][3]));
#pragma unroll
    for (int mt = 1; mt < 8; ++mt) {
      const float m0 = fmaxf(fmaxf(sc[mt][0], sc[mt][1]), fmaxf(sc[mt][2], sc[mt][3]));
      mx = fmaxf(mx, m0);
    }
    mx = fmaxf(mx, __shfl_xor(mx, 16));
    mx = fmaxf(mx, __shfl_xor(mx, 32));

    // ---- defer-max (T13): only rescale when the running max grows > 8 (log2 units) ----
    if (!__all(mx <= mrun + 8.f)) {
      const float mnew = fmaxf(mrun, mx);
      const float fac  = __builtin_amdgcn_exp2f(mrun - mnew);
      float facr[4];
#pragma unroll
      for (int r = 0; r < 4; ++r) facr[r] = __shfl(fac, g * 4 + r);
#pragma unroll
      for (int nt = 0; nt < 4; ++nt)
#pragma unroll
        for (int r = 0; r < 4; ++r) acc[nt][r] *= facr[r];
#pragma unroll
      for (int r = 0; r < 4; ++r) acc5[r] *= facr[r];
      mrun = mnew;
    }

    // ---- P = exp2(sc - mrun), pack bf16 (R1-proven f2bf path), write swizzled LDS ----
#pragma unroll
    for (int mt = 0; mt < 8; ++mt) {
      const float p0 = __builtin_amdgcn_exp2f(sc[mt][0] - mrun);
      const float p1 = __builtin_amdgcn_exp2f(sc[mt][1] - mrun);
      const float p2 = __builtin_amdgcn_exp2f(sc[mt][2] - mrun);
      const float p3 = __builtin_amdgcn_exp2f(sc[mt][3] - mrun);
      uint2v w;
      w.x = (unsigned)f2bf(p0) | ((unsigned)f2bf(p1) << 16);
      w.y = (unsigned)f2bf(p2) | ((unsigned)f2bf(p3) << 16);
      *(uint2v*)&Plds[wave][ql * 128 + ((2 * mt + gh) ^ qx) * 8 + 4 * glo] = w;
    }
    // ordering fence: P writes must not be reordered past the PV reads (TBAA insurance)
    asm volatile("" ::: "memory");

    // ---- PV + l-sum: acc[nt] += P(16q x 32k) * V(32k x 16d); acc5 += P * 1 ----
    __builtin_amdgcn_s_setprio(1);
#pragma unroll
    for (int s = 0; s < 4; ++s) {
      const bf16x8 pa = *(const bf16x8*)&Plds[wave][ql * 128 + ((s * 4 + g) ^ qx) * 8];
      acc5 = __builtin_amdgcn_mfma_f32_16x16x32_bf16(pa, ones, acc5, 0, 0, 0);
#pragma unroll
      for (int nt = 0; nt < 4; ++nt) {
        const bf16x8 bv = *(const bf16x8*)&Vlds[buf][(nt * 16 + ql) * 128 + ((s * 4 + g) ^ qx) * 8];
        acc[nt] = __builtin_amdgcn_mfma_f32_16x16x32_bf16(pa, bv, acc[nt], 0, 0, 0);
      }
    }
    __builtin_amdgcn_s_setprio(0);

    buf ^= 1;
  }

  // ---- epilogue: every lane already holds l for its q-rows in acc5 (all cols identical) ----
  float inv[4];
#pragma unroll
  for (int r = 0; r < 4; ++r) inv[r] = 1.f / acc5[r];
  float* obase = O + ((size_t)((b * H_ + h) * S_) + (size_t)(qt * 64 + wave * 16)) * 64;
#pragma unroll
  for (int nt = 0; nt < 4; ++nt)
#pragma unroll
    for (int r = 0; r < 4; ++r)
      obase[(size_t)(4 * g + r) * 64 + nt * 16 + ql] = acc[nt][r] * inv[r];
}

extern "C" void kernel_launch(void* const* d_in, const int* in_sizes, int n_in,
                              void* d_out, int out_size, void* d_ws, size_t ws_size,
                              hipStream_t stream) {
  const float* Q = (const float*)d_in[0];
  const float* K = (const float*)d_in[1];
  const float* V = (const float*)d_in[2];
  float* O = (float*)d_out;

  unsigned short* Kb = (unsigned short*)d_ws;
  unsigned short* Vt = Kb + (size_t)B_ * S_ * 64;

  prep_kernel<<<192, 256, 0, stream>>>(K, V, Kb, Vt);
  attn_kernel<<<B_ * H_ * (S_ / 64), 256, 0, stream>>>(Q, Kb, Vt, O);
}